// Round 17
// baseline (281.848 us; speedup 1.0000x reference)
//
#include <hip/hip_runtime.h>

#define VQ_D 64
#define VQ_K 512
#define W_FLAG 1.0e-4f

typedef float f32x4 __attribute__((ext_vector_type(4)));
typedef short bf16x8 __attribute__((ext_vector_type(8)));

// f32 -> bf16 RNE (no NaN inputs here)
__device__ __forceinline__ unsigned short f2bf(float f) {
    unsigned u = __float_as_uint(f);
    unsigned r = u + 0x7FFFu + ((u >> 16) & 1u);
    return (unsigned short)(r >> 16);
}
__device__ __forceinline__ float bf2f(unsigned short h) {
    return __uint_as_float(((unsigned)h) << 16);
}

// Monotone float->u32 (negatives below positives) — R4 lesson.
__device__ __forceinline__ unsigned ordkey(float f) {
    const unsigned u = __float_as_uint(f);
    return u ^ (unsigned)(((int)u >> 31) | (int)0x80000000);
}
__device__ __forceinline__ float ordkey_inv(unsigned k) {
    const unsigned u = (k & 0x80000000u) ? (k ^ 0x80000000u) : ~k;
    return __uint_as_float(u);
}

// ---------------------------------------------------------------------------
// numpy pairwise_sum replication for n=64 (proven bit-exact in R2).
// ---------------------------------------------------------------------------
__device__ __forceinline__ float np_sumsq64_g(const float* __restrict__ x)
{
    float r[8];
#pragma unroll
    for (int j = 0; j < 8; ++j) r[j] = __fmul_rn(x[j], x[j]);
#pragma unroll
    for (int i = 8; i < 64; i += 8) {
#pragma unroll
        for (int j = 0; j < 8; ++j)
            r[j] = __fadd_rn(r[j], __fmul_rn(x[i + j], x[i + j]));
    }
    return __fadd_rn(
        __fadd_rn(__fadd_rn(r[0], r[1]), __fadd_rn(r[2], r[3])),
        __fadd_rn(__fadd_rn(r[4], r[5]), __fadd_rn(r[6], r[7])));
}

// ---------------------------------------------------------------------------
// K0: prep (verified R8-R16): fragment-major bf16 hi/lo split + transposed
// f32 codebook + exact s2. Zeroes the flagged-row counter.
// ---------------------------------------------------------------------------
__global__ __launch_bounds__(256) void vq_prep(
    const float* __restrict__ emb,
    unsigned short* __restrict__ ebh,
    unsigned short* __restrict__ ebl,
    float* __restrict__ s2g,
    float* __restrict__ embT,
    unsigned* __restrict__ ctr)
{
    if (blockIdx.x == 0 && threadIdx.x == 0) ctr[0] = 0u;

    const int tg = blockIdx.x * 256 + threadIdx.x;   // 0..4095
    const int f  = tg >> 6;                          // fragment 0..63
    const int L  = tg & 63;                          // lane slot
    const int c  = (f >> 1) * 16 + (L & 15);         // code
    const int k0 = (f & 1) * 32 + (L >> 4) * 8;      // k base

    const float* e = emb + (size_t)c * VQ_D + k0;
    const f32x4 v0 = *reinterpret_cast<const f32x4*>(e);
    const f32x4 v1 = *reinterpret_cast<const f32x4*>(e + 4);
    bf16x8 h8, l8;
#pragma unroll
    for (int j = 0; j < 8; ++j) {
        const float fv = (j < 4) ? v0[j] : v1[j - 4];
        const unsigned short h = f2bf(fv);
        h8[j] = (short)h;
        l8[j] = (short)f2bf(__fsub_rn(fv, bf2f(h)));
        embT[(k0 + j) * VQ_K + c] = fv;              // transposed f32 copy
    }
    reinterpret_cast<bf16x8*>(ebh)[f * 64 + L] = h8;
    reinterpret_cast<bf16x8*>(ebl)[f * 64 + L] = l8;

    if (blockIdx.x < 2) {
        const int c2 = blockIdx.x * 256 + threadIdx.x;   // 0..511
        s2g[c2] = np_sumsq64_g(emb + (size_t)c2 * VQ_D);
    }
}

// ---------------------------------------------------------------------------
// K1: SCREEN R17 — B-resident waves, A streamed through LDS.
// Diagnosis (R12/R14/R16): MfmaUtil x dur == 21us (MFMA floor) in every
// variant; the 4-5x overhead is per-tile B-fragment L2 streaming (1GB,
// contended, ~2100cyc/tile vs ~150 issue). Fix: wave w pins B-fragments for
// its 64 codes in 64 VGPRs (loaded ONCE); 8 waves/block cover 512 codes.
// z streams in 16-row chunks: 128 threads stage+convert to LDS (identical
// f2bf ops, same values), all waves ds_read_b128 (conflict-free). Inner
// loop: ZERO VMEM — 4 ds_reads + 24 MFMA (12 indep 2-deep chains) +
// chunk-local min-update. Per-row 8-way top-2 merge in LDS (verified
// insert formula; packed (t,idx) keys keep first-min ties).
// ---------------------------------------------------------------------------
__global__ __launch_bounds__(512) void vq_screen(
    const float* __restrict__ z,
    const unsigned short* __restrict__ ebh,
    const unsigned short* __restrict__ ebl,
    const float* __restrict__ s2g,
    int* __restrict__ idxflag,
    unsigned* __restrict__ list,
    unsigned* __restrict__ ctr)
{
    __shared__ float s2s[VQ_K];                       // 2 KB
    __shared__ __align__(16) bf16x8 lah[128];         // 2 KB A-hi frags
    __shared__ __align__(16) bf16x8 lal[128];         // 2 KB A-lo frags
    __shared__ unsigned long long topbuf[16][8][2];   // 2 KB

    const int tid  = threadIdx.x;
    const int wid  = tid >> 6;           // wave 0..7 -> owns tiles 4w..4w+3
    const int lane = tid & 63;
    const int l15  = lane & 15;
    const int kg   = lane >> 4;
    const int rowbase = blockIdx.x * 128;

    s2s[tid] = s2g[tid];

    // ---- one-time: pin this wave's B fragments in registers (64 VGPR) ----
    bf16x8 Bh[4][2], Bl[4][2];
    {
        const bf16x8* GH = reinterpret_cast<const bf16x8*>(ebh);
        const bf16x8* GL = reinterpret_cast<const bf16x8*>(ebl);
#pragma unroll
        for (int tt = 0; tt < 4; ++tt) {
#pragma unroll
            for (int kc = 0; kc < 2; ++kc) {
                const int f = (wid * 4 + tt) * 2 + kc;
                Bh[tt][kc] = GH[f * 64 + lane];
                Bl[tt][kc] = GL[f * 64 + lane];
            }
        }
    }

#pragma unroll 1
    for (int chunk = 0; chunk < 8; ++chunk) {
        // ---- stage 16 rows: convert z -> bf16 hi/lo fragments in LDS ----
        // slot s (thread s<128): kc=s>>6, L=s&63; row=L&15, k0=kc*32+(L>>4)*8.
        // Identical f2bf/sub ops as the verified in-register path.
        if (tid < 128) {
            const int kc = tid >> 6, L = tid & 63;
            const int row = rowbase + chunk * 16 + (L & 15);
            const int k0  = kc * 32 + (L >> 4) * 8;
            const float* zp = z + (size_t)row * VQ_D + k0;
            const f32x4 v0 = *reinterpret_cast<const f32x4*>(zp);
            const f32x4 v1 = *reinterpret_cast<const f32x4*>(zp + 4);
            bf16x8 h8, l8;
#pragma unroll
            for (int j = 0; j < 8; ++j) {
                const float fv = (j < 4) ? v0[j] : v1[j - 4];
                const unsigned short h = f2bf(fv);
                h8[j] = (short)h;
                l8[j] = (short)f2bf(__fsub_rn(fv, bf2f(h)));
            }
            lah[tid] = h8;
            lal[tid] = l8;
        }
        __syncthreads();

        // ---- A fragments from LDS (all waves read the same slots) ----
        const bf16x8 Ah0 = lah[lane];        // kc=0
        const bf16x8 Al0 = lal[lane];
        const bf16x8 Ah1 = lah[64 + lane];   // kc=1
        const bf16x8 Al1 = lal[64 + lane];

        float m1[4], m2[4];
        int   i1[4];
#pragma unroll
        for (int j = 0; j < 4; ++j) { m1[j] = 3.4e38f; m2[j] = 3.4e38f; i1[j] = 0; }

#pragma unroll
        for (int tt = 0; tt < 4; ++tt) {
            const int tg = wid * 4 + tt;
            // 3 independent 2-deep chains (R7/R16-verified math).
            f32x4 aH = {0.f, 0.f, 0.f, 0.f};
            f32x4 aM = {0.f, 0.f, 0.f, 0.f};
            f32x4 aL = {0.f, 0.f, 0.f, 0.f};
            aH = __builtin_amdgcn_mfma_f32_16x16x32_bf16(Ah0, Bh[tt][0], aH, 0, 0, 0);
            aM = __builtin_amdgcn_mfma_f32_16x16x32_bf16(Ah0, Bl[tt][0], aM, 0, 0, 0);
            aL = __builtin_amdgcn_mfma_f32_16x16x32_bf16(Al0, Bh[tt][0], aL, 0, 0, 0);
            aH = __builtin_amdgcn_mfma_f32_16x16x32_bf16(Ah1, Bh[tt][1], aH, 0, 0, 0);
            aM = __builtin_amdgcn_mfma_f32_16x16x32_bf16(Ah1, Bl[tt][1], aM, 0, 0, 0);
            aL = __builtin_amdgcn_mfma_f32_16x16x32_bf16(Al1, Bh[tt][1], aL, 0, 0, 0);
            const float s2v = s2s[tg * 16 + l15];
            const int   cid = tg * 16 + l15;
#pragma unroll
            for (int j = 0; j < 4; ++j) {      // row = kg*4 + j (m89 layout)
                const float tv  = fmaf(-2.0f, (aH[j] + aM[j]) + aL[j], s2v);
                const float o1  = m1[j];
                m1[j] = fminf(o1, tv);
                i1[j] = (tv < o1) ? cid : i1[j];
                m2[j] = fminf(m2[j], fmaxf(tv, o1));
            }
        }

        // ---- wave-internal top-2 merge across the 16 l15 lanes ----
        unsigned long long k1[4], k2[4];
#pragma unroll
        for (int j = 0; j < 4; ++j) {
            k1[j] = (((unsigned long long)ordkey(m1[j])) << 32) | (unsigned)i1[j];
            k2[j] = (((unsigned long long)ordkey(m2[j])) << 32) | 0x1FFull;
        }
#pragma unroll
        for (int m = 1; m <= 8; m <<= 1) {
#pragma unroll
            for (int j = 0; j < 4; ++j) {
                const unsigned long long o1 = __shfl_xor(k1[j], m, 64);
                const unsigned long long o2 = __shfl_xor(k2[j], m, 64);
                const unsigned long long lo_ = (k1[j] < o1) ? k1[j] : o1;
                const unsigned long long hi_ = (k1[j] < o1) ? o1 : k1[j];
                const unsigned long long s2m = (k2[j] < o2) ? k2[j] : o2;
                k1[j] = lo_;
                k2[j] = (hi_ < s2m) ? hi_ : s2m;
            }
        }
        if (l15 == 0) {
#pragma unroll
            for (int j = 0; j < 4; ++j) {
                topbuf[kg * 4 + j][wid][0] = k1[j];
                topbuf[kg * 4 + j][wid][1] = k2[j];
            }
        }
        __syncthreads();   // topbuf visible; lah/lal free for next stage

        // ---- cross-wave merge: 16 threads, one row each ----
        if (tid < 16) {
            unsigned long long b1 = ~0ull, b2 = ~0ull;
#pragma unroll
            for (int w = 0; w < 8; ++w) {
                const unsigned long long ka = topbuf[tid][w][0];
                const unsigned long long kb = topbuf[tid][w][1];
                // insert ka (verified insert logic)
                const unsigned long long lo_ = (ka < b1) ? ka : b1;
                const unsigned long long hi_ = (ka < b1) ? b1 : ka;
                b1 = lo_;
                b2 = (hi_ < b2) ? hi_ : b2;
                // insert kb (kb >= ka so only competes for b2)
                b2 = (kb < b2) ? kb : b2;
            }
            const float t1 = ordkey_inv((unsigned)(b1 >> 32));
            const float t2 = ordkey_inv((unsigned)(b2 >> 32));
            const int idx  = (int)(b1 & 0x1FFull);
            const int row  = rowbase + chunk * 16 + tid;
            idxflag[row] = idx;
            if (__fsub_rn(t2, t1) <= W_FLAG) {
                const unsigned p = atomicAdd(ctr, 1u);
                list[p] = (unsigned)row;
            }
        }
    }
}

// ---------------------------------------------------------------------------
// K2: exact rescan (R14/R16-verified, byte-identical): one block per flagged
// row, early return, LDS z-row, np_sumsq64_g on LDS, c = tid.
// ---------------------------------------------------------------------------
__global__ __launch_bounds__(512) void vq_rescan(
    const float* __restrict__ z,
    const float* __restrict__ embT,
    const float* __restrict__ s2g,
    const unsigned* __restrict__ list,
    const unsigned* __restrict__ ctr,
    int* __restrict__ idxflag)
{
    __shared__ __align__(16) float zs[VQ_D];
    __shared__ unsigned long long wbest[8];
    const int tid  = threadIdx.x;
    const int wid  = tid >> 6;
    const int lane = tid & 63;
    const unsigned count = ctr[0];
    const unsigned i = blockIdx.x;       // one block per flagged row
    if (i >= count) return;

    const int row = (int)list[i];
    if (tid < VQ_D) zs[tid] = z[(size_t)row * VQ_D + tid];
    __syncthreads();

    const float s1 = np_sumsq64_g(zs);

    const int c = tid;
    float a = 0.f;
#pragma unroll
    for (int d = 0; d < VQ_D; ++d)
        a = fmaf(zs[d], embT[d * VQ_K + c], a);

    const float tv = __fadd_rn(__fsub_rn(s1, __fmul_rn(2.0f, a)), s2g[c]);
    // tv ~ 64 > 0 always -> raw-bit order fine (proven R2).
    unsigned long long best =
        (((unsigned long long)__float_as_uint(tv)) << 32) | (unsigned)c;
#pragma unroll
    for (int m = 1; m <= 32; m <<= 1) {
        const unsigned long long o = __shfl_xor(best, m, 64);
        best = (o < best) ? o : best;
    }
    if (lane == 0) wbest[wid] = best;
    __syncthreads();
    if (tid == 0) {
        unsigned long long b = wbest[0];
#pragma unroll
        for (int w = 1; w < 8; ++w) b = (wbest[w] < b) ? wbest[w] : b;
        idxflag[row] = (int)(b & 0x1FFull);
    }
}

// ---------------------------------------------------------------------------
// K3: streaming epilogue (R9-R16-verified, byte-identical). 4 lanes/row.
// ---------------------------------------------------------------------------
__global__ __launch_bounds__(256) void vq_epilogue(
    const float* __restrict__ z,
    const float* __restrict__ emb,
    const int* __restrict__ idxflag,
    float* __restrict__ zq_out,
    float* __restrict__ idx_out,
    double* __restrict__ partials)
{
    __shared__ double wsum[4];
    const int tid  = threadIdx.x;
    const int row  = blockIdx.x * 64 + (tid >> 2);
    const int seg  = tid & 3;
    const int idx  = idxflag[row] & 0x1FF;

    const float* zp = z + (size_t)row * VQ_D + seg * 16;
    const float* ep = emb + (size_t)idx * VQ_D + seg * 16;
    float* qp = zq_out + (size_t)row * VQ_D + seg * 16;

    double lsum = 0.0;
#pragma unroll
    for (int i = 0; i < 4; ++i) {
        const f32x4 zv = *reinterpret_cast<const f32x4*>(zp + i * 4);
        const f32x4 ev = *reinterpret_cast<const f32x4*>(ep + i * 4);
        f32x4 ov;
#pragma unroll
        for (int j = 0; j < 4; ++j) {
            const float d = __fsub_rn(ev[j], zv[j]);
            ov[j] = __fadd_rn(zv[j], d);
            lsum += (double)__fmul_rn(d, d);
        }
        *reinterpret_cast<f32x4*>(qp + i * 4) = ov;
    }
    if (seg == 0) idx_out[row] = (float)idx;

#pragma unroll
    for (int off = 32; off > 0; off >>= 1)
        lsum += __shfl_down(lsum, off, 64);
    const int lane = tid & 63, w = tid >> 6;
    if (lane == 0) wsum[w] = lsum;
    __syncthreads();
    if (tid == 0)
        partials[blockIdx.x] = wsum[0] + wsum[1] + wsum[2] + wsum[3];
}

// ---------------------------------------------------------------------------
// K4: reduce partials -> loss = 1.25 * sum / N.
// ---------------------------------------------------------------------------
__global__ __launch_bounds__(256) void vq_finalize_kernel(
    const double* __restrict__ partials, int nparts,
    float* __restrict__ loss_out, double inv_n)
{
    __shared__ double ws[4];
    double s = 0.0;
    for (int i = threadIdx.x; i < nparts; i += 256) s += partials[i];
#pragma unroll
    for (int off = 32; off > 0; off >>= 1)
        s += __shfl_down(s, off, 64);
    const int lane = threadIdx.x & 63, w = threadIdx.x >> 6;
    if (lane == 0) ws[w] = s;
    __syncthreads();
    if (threadIdx.x == 0)
        loss_out[0] = (float)(1.25 * (ws[0] + ws[1] + ws[2] + ws[3]) * inv_n);
}

// ---------------------------------------------------------------------------
// Fallback (proven R2 kernel) if ws too small.
// ---------------------------------------------------------------------------
__global__ __launch_bounds__(256) void vq_main_kernel(
    const float* __restrict__ z, const float* __restrict__ emb,
    float* __restrict__ zq_out, float* __restrict__ idx_out,
    double* __restrict__ partials, int rows, int use_atomic)
{
    __shared__ float s2[VQ_K];
    __shared__ double wsb[4];
    for (int k = threadIdx.x; k < VQ_K; k += 256)
        s2[k] = np_sumsq64_g(emb + (size_t)k * VQ_D);
    __syncthreads();
    const int row = blockIdx.x * 256 + threadIdx.x;
    double lsum = 0.0;
    if (row < rows) {
        float zr[VQ_D];
        const float* zp = z + (size_t)row * VQ_D;
#pragma unroll
        for (int d = 0; d < VQ_D; d += 4) {
            const float4 v = *reinterpret_cast<const float4*>(zp + d);
            zr[d] = v.x; zr[d+1] = v.y; zr[d+2] = v.z; zr[d+3] = v.w;
        }
        const float s1 = np_sumsq64_g(zr);
        float best = 3.4e38f; int bi = 0;
        for (int k = 0; k < VQ_K; k += 4) {
            const float* e0 = emb + (size_t)(k+0) * VQ_D;
            const float* e1 = emb + (size_t)(k+1) * VQ_D;
            const float* e2 = emb + (size_t)(k+2) * VQ_D;
            const float* e3 = emb + (size_t)(k+3) * VQ_D;
            float a0=0.f,a1=0.f,a2=0.f,a3=0.f;
#pragma unroll
            for (int d = 0; d < VQ_D; ++d) {
                const float zd = zr[d];
                a0 = fmaf(zd, e0[d], a0); a1 = fmaf(zd, e1[d], a1);
                a2 = fmaf(zd, e2[d], a2); a3 = fmaf(zd, e3[d], a3);
            }
            float t;
            t = __fadd_rn(__fsub_rn(s1, __fmul_rn(2.0f, a0)), s2[k+0]);
            if (t < best) { best = t; bi = k+0; }
            t = __fadd_rn(__fsub_rn(s1, __fmul_rn(2.0f, a1)), s2[k+1]);
            if (t < best) { best = t; bi = k+1; }
            t = __fadd_rn(__fsub_rn(s1, __fmul_rn(2.0f, a2)), s2[k+2]);
            if (t < best) { best = t; bi = k+2; }
            t = __fadd_rn(__fsub_rn(s1, __fmul_rn(2.0f, a3)), s2[k+3]);
            if (t < best) { best = t; bi = k+3; }
        }
        const float* eb = emb + (size_t)bi * VQ_D;
        float* zq = zq_out + (size_t)row * VQ_D;
#pragma unroll
        for (int d = 0; d < VQ_D; d += 4) {
            float4 ev, ov;
            ev.x = eb[d]; ev.y = eb[d+1]; ev.z = eb[d+2]; ev.w = eb[d+3];
            const float d0 = __fsub_rn(ev.x, zr[d]);
            const float d1 = __fsub_rn(ev.y, zr[d+1]);
            const float d2 = __fsub_rn(ev.z, zr[d+2]);
            const float d3 = __fsub_rn(ev.w, zr[d+3]);
            ov.x = __fadd_rn(zr[d], d0);   ov.y = __fadd_rn(zr[d+1], d1);
            ov.z = __fadd_rn(zr[d+2], d2); ov.w = __fadd_rn(zr[d+3], d3);
            *reinterpret_cast<float4*>(zq + d) = ov;
            lsum += (double)__fmul_rn(d0,d0) + (double)__fmul_rn(d1,d1)
                  + (double)__fmul_rn(d2,d2) + (double)__fmul_rn(d3,d3);
        }
        idx_out[row] = (float)bi;
    }
#pragma unroll
    for (int off = 32; off > 0; off >>= 1)
        lsum += __shfl_down(lsum, off, 64);
    const int lane = threadIdx.x & 63, w = threadIdx.x >> 6;
    if (lane == 0) wsb[w] = lsum;
    __syncthreads();
    if (threadIdx.x == 0) {
        const double bs = wsb[0] + wsb[1] + wsb[2] + wsb[3];
        if (use_atomic) atomicAdd(partials, bs);
        else partials[blockIdx.x] = bs;
    }
}

extern "C" void kernel_launch(void* const* d_in, const int* in_sizes, int n_in,
                              void* d_out, int out_size, void* d_ws, size_t ws_size,
                              hipStream_t stream) {
    const float* z   = (const float*)d_in[0];
    const float* emb = (const float*)d_in[1];
    float* out = (float*)d_out;

    const int zn   = in_sizes[0];        // 16777216
    const int rows = zn / VQ_D;          // 262144

    float* zq_out   = out;
    float* loss_out = out + zn;
    float* idx_out  = out + zn + 1;

    // ws: ebh 64K | ebl 64K | s2 2K | embT 128K | ctr 256B | list 1M |
    //     idxflag 1M | partials 32K
    const size_t OFF_EBL  = 65536;
    const size_t OFF_S2   = 131072;
    const size_t OFF_EMBT = 133120;
    const size_t OFF_CTR  = 264192;
    const size_t OFF_LIST = 264448;
    const size_t OFF_IDXF = OFF_LIST + (size_t)rows * 4;
    const size_t OFF_PART = OFF_IDXF + (size_t)rows * 4;
    const int eblocks = rows / 64;       // 4096 epilogue blocks
    const size_t need = OFF_PART + (size_t)eblocks * sizeof(double);

    if (ws_size >= need && (rows % 128) == 0) {
        unsigned short* ebh = (unsigned short*)d_ws;
        unsigned short* ebl = (unsigned short*)((char*)d_ws + OFF_EBL);
        float* s2g          = (float*)((char*)d_ws + OFF_S2);
        float* embT         = (float*)((char*)d_ws + OFF_EMBT);
        unsigned* ctr       = (unsigned*)((char*)d_ws + OFF_CTR);
        unsigned* list      = (unsigned*)((char*)d_ws + OFF_LIST);
        int* idxflag        = (int*)((char*)d_ws + OFF_IDXF);
        double* partials    = (double*)((char*)d_ws + OFF_PART);

        vq_prep<<<16, 256, 0, stream>>>(emb, ebh, ebl, s2g, embT, ctr);
        vq_screen<<<rows / 128, 512, 0, stream>>>(z, ebh, ebl, s2g,
                                                  idxflag, list, ctr);
        vq_rescan<<<8192, 512, 0, stream>>>(z, embT, s2g, list, ctr, idxflag);
        vq_epilogue<<<eblocks, 256, 0, stream>>>(z, emb, idxflag,
                                                 zq_out, idx_out, partials);
        vq_finalize_kernel<<<1, 256, 0, stream>>>(
            partials, eblocks, loss_out, 1.0 / (double)zn);
    } else {
        const int grid = (rows + 255) / 256;
        double* partials = (double*)d_ws;
        const int use_atomic = (ws_size < (size_t)grid * sizeof(double)) ? 1 : 0;
        if (use_atomic) hipMemsetAsync(d_ws, 0, sizeof(double), stream);
        vq_main_kernel<<<grid, 256, 0, stream>>>(z, emb, zq_out, idx_out,
                                                 partials, rows, use_atomic);
        vq_finalize_kernel<<<1, 256, 0, stream>>>(partials, use_atomic ? 1 : grid,
                                                  loss_out, 1.0 / (double)zn);
    }
}

// Round 18
// 146.608 us; speedup vs baseline: 1.9225x; 1.9225x over previous
//
#include <hip/hip_runtime.h>

#define VQ_D 64
#define VQ_K 512
#define W_FLAG 1.0e-4f

typedef float f32x4 __attribute__((ext_vector_type(4)));
typedef short bf16x8 __attribute__((ext_vector_type(8)));

// f32 -> bf16 RNE (no NaN inputs here)
__device__ __forceinline__ unsigned short f2bf(float f) {
    unsigned u = __float_as_uint(f);
    unsigned r = u + 0x7FFFu + ((u >> 16) & 1u);
    return (unsigned short)(r >> 16);
}
__device__ __forceinline__ float bf2f(unsigned short h) {
    return __uint_as_float(((unsigned)h) << 16);
}

// Monotone float->u32 (negatives below positives) — R4 lesson.
__device__ __forceinline__ unsigned ordkey(float f) {
    const unsigned u = __float_as_uint(f);
    return u ^ (unsigned)(((int)u >> 31) | (int)0x80000000);
}
__device__ __forceinline__ float ordkey_inv(unsigned k) {
    const unsigned u = (k & 0x80000000u) ? (k ^ 0x80000000u) : ~k;
    return __uint_as_float(u);
}

// ---------------------------------------------------------------------------
// numpy pairwise_sum replication for n=64 (proven bit-exact in R2).
// ---------------------------------------------------------------------------
__device__ __forceinline__ float np_sumsq64_g(const float* __restrict__ x)
{
    float r[8];
#pragma unroll
    for (int j = 0; j < 8; ++j) r[j] = __fmul_rn(x[j], x[j]);
#pragma unroll
    for (int i = 8; i < 64; i += 8) {
#pragma unroll
        for (int j = 0; j < 8; ++j)
            r[j] = __fadd_rn(r[j], __fmul_rn(x[i + j], x[i + j]));
    }
    return __fadd_rn(
        __fadd_rn(__fadd_rn(r[0], r[1]), __fadd_rn(r[2], r[3])),
        __fadd_rn(__fadd_rn(r[4], r[5]), __fadd_rn(r[6], r[7])));
}

// ---------------------------------------------------------------------------
// K0: prep (verified R8-R16): fragment-major bf16 hi/lo split + transposed
// f32 codebook + exact s2. Zeroes the flagged-row counter.
// ---------------------------------------------------------------------------
__global__ __launch_bounds__(256) void vq_prep(
    const float* __restrict__ emb,
    unsigned short* __restrict__ ebh,
    unsigned short* __restrict__ ebl,
    float* __restrict__ s2g,
    float* __restrict__ embT,
    unsigned* __restrict__ ctr)
{
    if (blockIdx.x == 0 && threadIdx.x == 0) ctr[0] = 0u;

    const int tg = blockIdx.x * 256 + threadIdx.x;   // 0..4095
    const int f  = tg >> 6;                          // fragment 0..63
    const int L  = tg & 63;                          // lane slot
    const int c  = (f >> 1) * 16 + (L & 15);         // code
    const int k0 = (f & 1) * 32 + (L >> 4) * 8;      // k base

    const float* e = emb + (size_t)c * VQ_D + k0;
    const f32x4 v0 = *reinterpret_cast<const f32x4*>(e);
    const f32x4 v1 = *reinterpret_cast<const f32x4*>(e + 4);
    bf16x8 h8, l8;
#pragma unroll
    for (int j = 0; j < 8; ++j) {
        const float fv = (j < 4) ? v0[j] : v1[j - 4];
        const unsigned short h = f2bf(fv);
        h8[j] = (short)h;
        l8[j] = (short)f2bf(__fsub_rn(fv, bf2f(h)));
        embT[(k0 + j) * VQ_K + c] = fv;              // transposed f32 copy
    }
    reinterpret_cast<bf16x8*>(ebh)[f * 64 + L] = h8;
    reinterpret_cast<bf16x8*>(ebl)[f * 64 + L] = l8;

    if (blockIdx.x < 2) {
        const int c2 = blockIdx.x * 256 + threadIdx.x;   // 0..511
        s2g[c2] = np_sumsq64_g(emb + (size_t)c2 * VQ_D);
    }
}

// ---------------------------------------------------------------------------
// K1: SCREEN R18 — R14-verified LDS-staged screen with ONE change: codebook
// staged in TWO 64KB half-passes (256 codes each) instead of one 128KB
// stage. LDS 130KB->66KB lifts occupancy 1->2 blocks/CU (17%->~33%), the
// exact variable separating R12 (87us, 33% occ) from R14 (95us, 17% occ).
// 4 barriers/block total (not R17's 16). Accumulators persist across passes
// (same wave, same m1/m2/i1) — no merge change. All numerics byte-identical
// to R14/R16 (A-frags, 3-chain MFMA, min-update, lane merge, flag).
// ---------------------------------------------------------------------------
__global__ __launch_bounds__(512) void vq_screen(
    const float* __restrict__ z,
    const unsigned short* __restrict__ ebh,
    const unsigned short* __restrict__ ebl,
    const float* __restrict__ s2g,
    int* __restrict__ idxflag,
    unsigned* __restrict__ list,
    unsigned* __restrict__ ctr)
{
    __shared__ __align__(16) bf16x8 lbh[2048];   // 32 KB (half codebook hi)
    __shared__ __align__(16) bf16x8 lbl[2048];   // 32 KB (half codebook lo)
    __shared__ float s2s[VQ_K];                  // 2 KB

    const int tid  = threadIdx.x;
    const int wid  = tid >> 6;
    const int lane = tid & 63;
    const int l15  = lane & 15;
    const int kg   = lane >> 4;
    const int rowbase = blockIdx.x * 256 + wid * 32;   // 8 waves x 32 rows

    s2s[tid] = s2g[tid];                 // 512 threads cover VQ_K

    // A fragments (R12/R14-verified): row = rg*16+l15, k = kc*32+kg*8+j.
    bf16x8 Ah[2][2], Al[2][2];
#pragma unroll
    for (int rg = 0; rg < 2; ++rg) {
#pragma unroll
        for (int kc = 0; kc < 2; ++kc) {
            const float* zp = z + (size_t)(rowbase + rg * 16 + l15) * VQ_D
                            + kc * 32 + kg * 8;
            const f32x4 v0 = *reinterpret_cast<const f32x4*>(zp);
            const f32x4 v1 = *reinterpret_cast<const f32x4*>(zp + 4);
            bf16x8 ah, al;
#pragma unroll
            for (int j = 0; j < 8; ++j) {
                const float fv = (j < 4) ? v0[j] : v1[j - 4];
                const unsigned short h = f2bf(fv);
                ah[j] = (short)h;
                al[j] = (short)f2bf(__fsub_rn(fv, bf2f(h)));
            }
            Ah[rg][kc] = ah; Al[rg][kc] = al;
        }
    }

    float m1[2][4], m2[2][4];
    int   i1[2][4];
#pragma unroll
    for (int rg = 0; rg < 2; ++rg)
#pragma unroll
        for (int j = 0; j < 4; ++j) {
            m1[rg][j] = 3.4e38f; m2[rg][j] = 3.4e38f; i1[rg][j] = 0;
        }

    const bf16x8* GH = reinterpret_cast<const bf16x8*>(ebh);
    const bf16x8* GL = reinterpret_cast<const bf16x8*>(ebl);

#pragma unroll 1
    for (int p = 0; p < 2; ++p) {
        __syncthreads();                 // prev half fully consumed (or s2s)
        // stage 256 codes (frags p*32..p*32+31): 4 units hi + 4 lo / thread
#pragma unroll
        for (int i = 0; i < 4; ++i) {
            lbh[i * 512 + tid] = GH[p * 2048 + i * 512 + tid];
            lbl[i * 512 + tid] = GL[p * 2048 + i * 512 + tid];
        }
        __syncthreads();

#pragma unroll 4
        for (int ttl = 0; ttl < 16; ++ttl) {
            const int t = p * 16 + ttl;            // global tile id
            const bf16x8 Bh0 = lbh[(ttl * 2 + 0) * 64 + lane];
            const bf16x8 Bl0 = lbl[(ttl * 2 + 0) * 64 + lane];
            const bf16x8 Bh1 = lbh[(ttl * 2 + 1) * 64 + lane];
            const bf16x8 Bl1 = lbl[(ttl * 2 + 1) * 64 + lane];
            const float s2v = s2s[t * 16 + l15];
            const int   cid = t * 16 + l15;
#pragma unroll
            for (int rg = 0; rg < 2; ++rg) {
                // 3 independent 2-deep chains (R7/R16-verified math).
                f32x4 aH = {0.f, 0.f, 0.f, 0.f};
                f32x4 aM = {0.f, 0.f, 0.f, 0.f};
                f32x4 aL = {0.f, 0.f, 0.f, 0.f};
                aH = __builtin_amdgcn_mfma_f32_16x16x32_bf16(Ah[rg][0], Bh0, aH, 0, 0, 0);
                aM = __builtin_amdgcn_mfma_f32_16x16x32_bf16(Ah[rg][0], Bl0, aM, 0, 0, 0);
                aL = __builtin_amdgcn_mfma_f32_16x16x32_bf16(Al[rg][0], Bh0, aL, 0, 0, 0);
                aH = __builtin_amdgcn_mfma_f32_16x16x32_bf16(Ah[rg][1], Bh1, aH, 0, 0, 0);
                aM = __builtin_amdgcn_mfma_f32_16x16x32_bf16(Ah[rg][1], Bl1, aM, 0, 0, 0);
                aL = __builtin_amdgcn_mfma_f32_16x16x32_bf16(Al[rg][1], Bh1, aL, 0, 0, 0);
#pragma unroll
                for (int j = 0; j < 4; ++j) {      // row = kg*4 + j (m89)
                    const float tv  = fmaf(-2.0f, (aH[j] + aM[j]) + aL[j], s2v);
                    const float o1  = m1[rg][j];
                    m1[rg][j] = fminf(o1, tv);
                    i1[rg][j] = (tv < o1) ? cid : i1[rg][j];
                    m2[rg][j] = fminf(m2[rg][j], fmaxf(tv, o1));
                }
            }
        }
    }

    // Merge top-2 across the 16 l15 lanes (R14-verified); write idx|flag.
#pragma unroll
    for (int rg = 0; rg < 2; ++rg) {
        unsigned long long k1[4], k2[4];
#pragma unroll
        for (int j = 0; j < 4; ++j) {
            k1[j] = (((unsigned long long)ordkey(m1[rg][j])) << 32) | (unsigned)i1[rg][j];
            k2[j] = (((unsigned long long)ordkey(m2[rg][j])) << 32) | 0x1FFull;
        }
#pragma unroll
        for (int m = 1; m <= 8; m <<= 1) {
#pragma unroll
            for (int j = 0; j < 4; ++j) {
                const unsigned long long o1 = __shfl_xor(k1[j], m, 64);
                const unsigned long long o2 = __shfl_xor(k2[j], m, 64);
                const unsigned long long lo_ = (k1[j] < o1) ? k1[j] : o1;
                const unsigned long long hi_ = (k1[j] < o1) ? o1 : k1[j];
                const unsigned long long s2m = (k2[j] < o2) ? k2[j] : o2;
                k1[j] = lo_;
                k2[j] = (hi_ < s2m) ? hi_ : s2m;
            }
        }
        if (l15 == 0) {
#pragma unroll
            for (int j = 0; j < 4; ++j) {
                const float t1 = ordkey_inv((unsigned)(k1[j] >> 32));
                const float t2 = ordkey_inv((unsigned)(k2[j] >> 32));
                const int idx = (int)(k1[j] & 0x1FFull);
                const int row = rowbase + rg * 16 + kg * 4 + j;
                idxflag[row] = idx;
                if (__fsub_rn(t2, t1) <= W_FLAG) {
                    const unsigned p = atomicAdd(ctr, 1u);
                    list[p] = (unsigned)row;
                }
            }
        }
    }
}

// ---------------------------------------------------------------------------
// K2: exact rescan (R14/R16-verified, byte-identical): one block per flagged
// row, early return, LDS z-row, np_sumsq64_g on LDS, c = tid.
// ---------------------------------------------------------------------------
__global__ __launch_bounds__(512) void vq_rescan(
    const float* __restrict__ z,
    const float* __restrict__ embT,
    const float* __restrict__ s2g,
    const unsigned* __restrict__ list,
    const unsigned* __restrict__ ctr,
    int* __restrict__ idxflag)
{
    __shared__ __align__(16) float zs[VQ_D];
    __shared__ unsigned long long wbest[8];
    const int tid  = threadIdx.x;
    const int wid  = tid >> 6;
    const int lane = tid & 63;
    const unsigned count = ctr[0];
    const unsigned i = blockIdx.x;       // one block per flagged row
    if (i >= count) return;

    const int row = (int)list[i];
    if (tid < VQ_D) zs[tid] = z[(size_t)row * VQ_D + tid];
    __syncthreads();

    const float s1 = np_sumsq64_g(zs);

    const int c = tid;
    float a = 0.f;
#pragma unroll
    for (int d = 0; d < VQ_D; ++d)
        a = fmaf(zs[d], embT[d * VQ_K + c], a);

    const float tv = __fadd_rn(__fsub_rn(s1, __fmul_rn(2.0f, a)), s2g[c]);
    // tv ~ 64 > 0 always -> raw-bit order fine (proven R2).
    unsigned long long best =
        (((unsigned long long)__float_as_uint(tv)) << 32) | (unsigned)c;
#pragma unroll
    for (int m = 1; m <= 32; m <<= 1) {
        const unsigned long long o = __shfl_xor(best, m, 64);
        best = (o < best) ? o : best;
    }
    if (lane == 0) wbest[wid] = best;
    __syncthreads();
    if (tid == 0) {
        unsigned long long b = wbest[0];
#pragma unroll
        for (int w = 1; w < 8; ++w) b = (wbest[w] < b) ? wbest[w] : b;
        idxflag[row] = (int)(b & 0x1FFull);
    }
}

// ---------------------------------------------------------------------------
// K3: streaming epilogue (R9-R16-verified, byte-identical). 4 lanes/row.
// ---------------------------------------------------------------------------
__global__ __launch_bounds__(256) void vq_epilogue(
    const float* __restrict__ z,
    const float* __restrict__ emb,
    const int* __restrict__ idxflag,
    float* __restrict__ zq_out,
    float* __restrict__ idx_out,
    double* __restrict__ partials)
{
    __shared__ double wsum[4];
    const int tid  = threadIdx.x;
    const int row  = blockIdx.x * 64 + (tid >> 2);
    const int seg  = tid & 3;
    const int idx  = idxflag[row] & 0x1FF;

    const float* zp = z + (size_t)row * VQ_D + seg * 16;
    const float* ep = emb + (size_t)idx * VQ_D + seg * 16;
    float* qp = zq_out + (size_t)row * VQ_D + seg * 16;

    double lsum = 0.0;
#pragma unroll
    for (int i = 0; i < 4; ++i) {
        const f32x4 zv = *reinterpret_cast<const f32x4*>(zp + i * 4);
        const f32x4 ev = *reinterpret_cast<const f32x4*>(ep + i * 4);
        f32x4 ov;
#pragma unroll
        for (int j = 0; j < 4; ++j) {
            const float d = __fsub_rn(ev[j], zv[j]);
            ov[j] = __fadd_rn(zv[j], d);
            lsum += (double)__fmul_rn(d, d);
        }
        *reinterpret_cast<f32x4*>(qp + i * 4) = ov;
    }
    if (seg == 0) idx_out[row] = (float)idx;

#pragma unroll
    for (int off = 32; off > 0; off >>= 1)
        lsum += __shfl_down(lsum, off, 64);
    const int lane = tid & 63, w = tid >> 6;
    if (lane == 0) wsum[w] = lsum;
    __syncthreads();
    if (tid == 0)
        partials[blockIdx.x] = wsum[0] + wsum[1] + wsum[2] + wsum[3];
}

// ---------------------------------------------------------------------------
// K4: reduce partials -> loss = 1.25 * sum / N.
// ---------------------------------------------------------------------------
__global__ __launch_bounds__(256) void vq_finalize_kernel(
    const double* __restrict__ partials, int nparts,
    float* __restrict__ loss_out, double inv_n)
{
    __shared__ double ws[4];
    double s = 0.0;
    for (int i = threadIdx.x; i < nparts; i += 256) s += partials[i];
#pragma unroll
    for (int off = 32; off > 0; off >>= 1)
        s += __shfl_down(s, off, 64);
    const int lane = threadIdx.x & 63, w = threadIdx.x >> 6;
    if (lane == 0) ws[w] = s;
    __syncthreads();
    if (threadIdx.x == 0)
        loss_out[0] = (float)(1.25 * (ws[0] + ws[1] + ws[2] + ws[3]) * inv_n);
}

// ---------------------------------------------------------------------------
// Fallback (proven R2 kernel) if ws too small.
// ---------------------------------------------------------------------------
__global__ __launch_bounds__(256) void vq_main_kernel(
    const float* __restrict__ z, const float* __restrict__ emb,
    float* __restrict__ zq_out, float* __restrict__ idx_out,
    double* __restrict__ partials, int rows, int use_atomic)
{
    __shared__ float s2[VQ_K];
    __shared__ double wsb[4];
    for (int k = threadIdx.x; k < VQ_K; k += 256)
        s2[k] = np_sumsq64_g(emb + (size_t)k * VQ_D);
    __syncthreads();
    const int row = blockIdx.x * 256 + threadIdx.x;
    double lsum = 0.0;
    if (row < rows) {
        float zr[VQ_D];
        const float* zp = z + (size_t)row * VQ_D;
#pragma unroll
        for (int d = 0; d < VQ_D; d += 4) {
            const float4 v = *reinterpret_cast<const float4*>(zp + d);
            zr[d] = v.x; zr[d+1] = v.y; zr[d+2] = v.z; zr[d+3] = v.w;
        }
        const float s1 = np_sumsq64_g(zr);
        float best = 3.4e38f; int bi = 0;
        for (int k = 0; k < VQ_K; k += 4) {
            const float* e0 = emb + (size_t)(k+0) * VQ_D;
            const float* e1 = emb + (size_t)(k+1) * VQ_D;
            const float* e2 = emb + (size_t)(k+2) * VQ_D;
            const float* e3 = emb + (size_t)(k+3) * VQ_D;
            float a0=0.f,a1=0.f,a2=0.f,a3=0.f;
#pragma unroll
            for (int d = 0; d < VQ_D; ++d) {
                const float zd = zr[d];
                a0 = fmaf(zd, e0[d], a0); a1 = fmaf(zd, e1[d], a1);
                a2 = fmaf(zd, e2[d], a2); a3 = fmaf(zd, e3[d], a3);
            }
            float t;
            t = __fadd_rn(__fsub_rn(s1, __fmul_rn(2.0f, a0)), s2[k+0]);
            if (t < best) { best = t; bi = k+0; }
            t = __fadd_rn(__fsub_rn(s1, __fmul_rn(2.0f, a1)), s2[k+1]);
            if (t < best) { best = t; bi = k+1; }
            t = __fadd_rn(__fsub_rn(s1, __fmul_rn(2.0f, a2)), s2[k+2]);
            if (t < best) { best = t; bi = k+2; }
            t = __fadd_rn(__fsub_rn(s1, __fmul_rn(2.0f, a3)), s2[k+3]);
            if (t < best) { best = t; bi = k+3; }
        }
        const float* eb = emb + (size_t)bi * VQ_D;
        float* zq = zq_out + (size_t)row * VQ_D;
#pragma unroll
        for (int d = 0; d < VQ_D; d += 4) {
            float4 ev, ov;
            ev.x = eb[d]; ev.y = eb[d+1]; ev.z = eb[d+2]; ev.w = eb[d+3];
            const float d0 = __fsub_rn(ev.x, zr[d]);
            const float d1 = __fsub_rn(ev.y, zr[d+1]);
            const float d2 = __fsub_rn(ev.z, zr[d+2]);
            const float d3 = __fsub_rn(ev.w, zr[d+3]);
            ov.x = __fadd_rn(zr[d], d0);   ov.y = __fadd_rn(zr[d+1], d1);
            ov.z = __fadd_rn(zr[d+2], d2); ov.w = __fadd_rn(zr[d+3], d3);
            *reinterpret_cast<float4*>(zq + d) = ov;
            lsum += (double)__fmul_rn(d0,d0) + (double)__fmul_rn(d1,d1)
                  + (double)__fmul_rn(d2,d2) + (double)__fmul_rn(d3,d3);
        }
        idx_out[row] = (float)bi;
    }
#pragma unroll
    for (int off = 32; off > 0; off >>= 1)
        lsum += __shfl_down(lsum, off, 64);
    const int lane = threadIdx.x & 63, w = threadIdx.x >> 6;
    if (lane == 0) wsb[w] = lsum;
    __syncthreads();
    if (threadIdx.x == 0) {
        const double bs = wsb[0] + wsb[1] + wsb[2] + wsb[3];
        if (use_atomic) atomicAdd(partials, bs);
        else partials[blockIdx.x] = bs;
    }
}

extern "C" void kernel_launch(void* const* d_in, const int* in_sizes, int n_in,
                              void* d_out, int out_size, void* d_ws, size_t ws_size,
                              hipStream_t stream) {
    const float* z   = (const float*)d_in[0];
    const float* emb = (const float*)d_in[1];
    float* out = (float*)d_out;

    const int zn   = in_sizes[0];        // 16777216
    const int rows = zn / VQ_D;          // 262144

    float* zq_out   = out;
    float* loss_out = out + zn;
    float* idx_out  = out + zn + 1;

    // ws: ebh 64K | ebl 64K | s2 2K | embT 128K | ctr 256B | list 1M |
    //     idxflag 1M | partials 32K
    const size_t OFF_EBL  = 65536;
    const size_t OFF_S2   = 131072;
    const size_t OFF_EMBT = 133120;
    const size_t OFF_CTR  = 264192;
    const size_t OFF_LIST = 264448;
    const size_t OFF_IDXF = OFF_LIST + (size_t)rows * 4;
    const size_t OFF_PART = OFF_IDXF + (size_t)rows * 4;
    const int eblocks = rows / 64;       // 4096 epilogue blocks
    const size_t need = OFF_PART + (size_t)eblocks * sizeof(double);

    if (ws_size >= need && (rows % 256) == 0) {
        unsigned short* ebh = (unsigned short*)d_ws;
        unsigned short* ebl = (unsigned short*)((char*)d_ws + OFF_EBL);
        float* s2g          = (float*)((char*)d_ws + OFF_S2);
        float* embT         = (float*)((char*)d_ws + OFF_EMBT);
        unsigned* ctr       = (unsigned*)((char*)d_ws + OFF_CTR);
        unsigned* list      = (unsigned*)((char*)d_ws + OFF_LIST);
        int* idxflag        = (int*)((char*)d_ws + OFF_IDXF);
        double* partials    = (double*)((char*)d_ws + OFF_PART);

        vq_prep<<<16, 256, 0, stream>>>(emb, ebh, ebl, s2g, embT, ctr);
        vq_screen<<<rows / 256, 512, 0, stream>>>(z, ebh, ebl, s2g,
                                                  idxflag, list, ctr);
        vq_rescan<<<8192, 512, 0, stream>>>(z, embT, s2g, list, ctr, idxflag);
        vq_epilogue<<<eblocks, 256, 0, stream>>>(z, emb, idxflag,
                                                 zq_out, idx_out, partials);
        vq_finalize_kernel<<<1, 256, 0, stream>>>(
            partials, eblocks, loss_out, 1.0 / (double)zn);
    } else {
        const int grid = (rows + 255) / 256;
        double* partials = (double*)d_ws;
        const int use_atomic = (ws_size < (size_t)grid * sizeof(double)) ? 1 : 0;
        if (use_atomic) hipMemsetAsync(d_ws, 0, sizeof(double), stream);
        vq_main_kernel<<<grid, 256, 0, stream>>>(z, emb, zq_out, idx_out,
                                                 partials, rows, use_atomic);
        vq_finalize_kernel<<<1, 256, 0, stream>>>(partials, use_atomic ? 1 : grid,
                                                  loss_out, 1.0 / (double)zn);
    }
}